// Round 15
// baseline (250.143 us; speedup 1.0000x reference)
//
#include <hip/hip_runtime.h>
#include <hip/hip_bf16.h>
#include <stdint.h>

// Problem constants (fixed by the reference)
#define B_    4
#define N_    2048
#define DIM_  1024
#define H_    8
#define HD_   128
#define MTOK  (B_ * N_)          // 8192 tokens
#define SCALE_  0.08838834764831845f   // HD^-0.5
#define LOG2E_  1.4426950408889634f
#define QSCALE_ (SCALE_ * LOG2E_)      // folded into Q projection epilogue

typedef unsigned short u16;
typedef __attribute__((ext_vector_type(4)))  float f32x4;
typedef __attribute__((ext_vector_type(16))) float f32x16;
typedef __attribute__((ext_vector_type(8)))  short s16x8;   // 8 bf16 — MFMA A/B frag
typedef __attribute__((ext_vector_type(8)))  u16  u16x8;
typedef __attribute__((ext_vector_type(4)))  u16  u16x4;
typedef __attribute__((ext_vector_type(4)))  unsigned u32x4;

__device__ __forceinline__ u16 f2bf(float f) {
    uint32_t i = __builtin_bit_cast(uint32_t, f);
    return (u16)((i + 0x7FFFu + ((i >> 16) & 1u)) >> 16);   // RNE
}
__device__ __forceinline__ unsigned pk_bf16(float a, float b) {
    unsigned r;
    asm("v_cvt_pk_bf16_f32 %0, %1, %2" : "=v"(r) : "v"(a), "v"(b));
    return r;
}
__device__ __forceinline__ void pl32_swap(unsigned &a, unsigned &b) {
    asm volatile("v_permlane32_swap_b32 %0, %1" : "+v"(a), "+v"(b));
}
__device__ __forceinline__ void gl_lds16(const u16* g, u16* l) {
    __builtin_amdgcn_global_load_lds((const __attribute__((address_space(1))) void*)g,
                                     (__attribute__((address_space(3))) void*)l,
                                     16, 0, 0);
}

// ---------------------------------------------------------------- fused prep kernel
// One launch: [0,12288) cvt3 q/k/v f32->bf16 ; [12288,14336) cvt_w4 weights.
__global__ __launch_bounds__(256) void prep(const float* __restrict__ q,
                                            const float* __restrict__ k,
                                            const float* __restrict__ v,
                                            const float* __restrict__ Wq,
                                            const float* __restrict__ Wk,
                                            const float* __restrict__ Wv,
                                            const float* __restrict__ Wp,
                                            u16* __restrict__ qb,
                                            u16* __restrict__ wqb) {
    const int bid = blockIdx.x, tid = threadIdx.x;
    if (bid < 12288) {
        const int sl = bid >> 12, x = bid & 4095;
        const float* s = sl == 0 ? q : sl == 1 ? k : v;
        u16* d = qb + (size_t)sl * (8u << 20);
        int i = (x * 256 + tid) * 8;
        float4 a = *(const float4*)(s + i);
        float4 b = *(const float4*)(s + i + 4);
        u32x4 w = {pk_bf16(a.x, a.y), pk_bf16(a.z, a.w), pk_bf16(b.x, b.y), pk_bf16(b.z, b.w)};
        *(u16x8*)(d + i) = __builtin_bit_cast(u16x8, w);
    } else {
        const int sub = bid - 12288, sl = sub >> 9, x = sub & 511;
        const float* s = sl == 0 ? Wq : sl == 1 ? Wk : sl == 2 ? Wv : Wp;
        u16* d = wqb + (size_t)sl * (DIM_ * DIM_);
        int i = (x * 256 + tid) * 8;
        float4 a = *(const float4*)(s + i);
        float4 b = *(const float4*)(s + i + 4);
        u32x4 w = {pk_bf16(a.x, a.y), pk_bf16(a.z, a.w), pk_bf16(b.x, b.y), pk_bf16(b.z, b.w)};
        *(u16x8*)(d + i) = __builtin_bit_cast(u16x8, w);
    }
}

// ---------------------------------------------------------------- gate permute (lane-coalesced)
// tP4 (f32x4 units): idx = (((b*32+it)*2+hl)*8 + jj)*2048 + q
//   value[e] = trans[b][q][64*it + 32*(jj>>2) + 8*(jj&3) + 4*hl + e]
__global__ __launch_bounds__(256) void gate_permute(const float* __restrict__ trans,
                                                    float* __restrict__ tP) {
    __shared__ float T[64][68];
    const int sub = blockIdx.x;
    const int it = sub & 31, qc = (sub >> 5) & 31, b = sub >> 10;
    const float* ib = trans + (size_t)b * N_ * N_;
    const int q0 = qc * 64;
    const int lr = threadIdx.x >> 4, lc = threadIdx.x & 15;
    #pragma unroll
    for (int i = 0; i < 4; i++) {
        int row = i * 16 + lr;
        f32x4 vv = *(const f32x4*)(ib + (size_t)(q0 + row) * N_ + it * 64 + lc * 4);
        *(f32x4*)(&T[row][lc * 4]) = vv;
    }
    __syncthreads();
    const int qi = threadIdx.x & 63, grp = threadIdx.x >> 6;
    const int hl = grp & 1, half = grp >> 1;
    f32x4* tp4 = (f32x4*)tP;
    const size_t base = (((size_t)(b * 32 + it) * 2 + hl) * 8 + half * 4) * 2048 + q0 + qi;
    #pragma unroll
    for (int jj2 = 0; jj2 < 4; jj2++) {
        f32x4 vv = *(const f32x4*)(&T[qi][32 * half + 8 * jj2 + 4 * hl]);
        tp4[base + (size_t)jj2 * 2048] = vv;
    }
}

// ---------------------------------------------------------------- fused QKV projection GEMM
// z selects (A, Bt, Cout, scale, epilogue): z<2 -> head-split [B,H,N,HD] (Q,K);
// z==2 -> transposed [B,H,HD,N] (V).  A/C stride 8M u16; Bt stride 1M u16.
__global__ __launch_bounds__(256) void gemm_qkv(const u16* __restrict__ Abase,
                                                const u16* __restrict__ Wbase,
                                                u16* __restrict__ Cbase) {
    __shared__ __align__(16) u16 lga[128 * 64];
    __shared__ __align__(16) u16 lgb[128 * 64];
    const int tid  = threadIdx.x;
    const int lane = tid & 63, wave = tid >> 6;
    const int wm = wave >> 1, wn = wave & 1;
    const int z = blockIdx.z;
    const u16* A  = Abase + (size_t)z * (8u << 20);
    const u16* Bt = Wbase + (size_t)z * (DIM_ * DIM_);
    u16* Cout     = Cbase + (size_t)z * (8u << 20);
    const float scale = (z == 0) ? QSCALE_ : 1.0f;
    int lin = blockIdx.x + gridDim.x * blockIdx.y;
    int w   = (lin & 7) * 64 + (lin >> 3);
    const int row0 = (w >> 3) * 128, col0 = (w & 7) * 128;

    f32x4 acc[4][4] = {};

    auto stageLds = [&](const u16* G, u16* L, int rowbase, int k0) {
        #pragma unroll
        for (int i = 0; i < 4; i++) {
            int rb = wave * 32 + i * 8;
            int r  = rb + (lane >> 3);
            int cc = (lane & 7) ^ (lane >> 3);
            gl_lds16(G + (size_t)(rowbase + r) * DIM_ + k0 + cc * 8, L + rb * 64);
        }
    };

    for (int k0 = 0; k0 < DIM_; k0 += 64) {
        stageLds(A,  lga, row0, k0);
        stageLds(Bt, lgb, col0, k0);
        __syncthreads();
        #pragma unroll
        for (int kk = 0; kk < 2; kk++) {
            s16x8 af[4], bfr[4];
            #pragma unroll
            for (int mi = 0; mi < 4; mi++) {
                int r = wm * 64 + mi * 16 + (lane & 15);
                int sc = (kk * 4 + (lane >> 4)) ^ (lane & 7);
                af[mi] = *(const s16x8*)(&lga[r * 64 + sc * 8]);
            }
            #pragma unroll
            for (int ni = 0; ni < 4; ni++) {
                int r = wn * 64 + ni * 16 + (lane & 15);
                int sc = (kk * 4 + (lane >> 4)) ^ (lane & 7);
                bfr[ni] = *(const s16x8*)(&lgb[r * 64 + sc * 8]);
            }
            #pragma unroll
            for (int mi = 0; mi < 4; mi++)
                #pragma unroll
                for (int ni = 0; ni < 4; ni++)
                    acc[mi][ni] = __builtin_amdgcn_mfma_f32_16x16x32_bf16(
                        af[mi], bfr[ni], acc[mi][ni], 0, 0, 0);
        }
        __syncthreads();
    }

    #pragma unroll
    for (int mi = 0; mi < 4; mi++) {
        #pragma unroll
        for (int ni = 0; ni < 4; ni++) {
            #pragma unroll
            for (int r = 0; r < 4; r++) {
                int grow = row0 + wm * 64 + mi * 16 + ((lane >> 4) << 2) + r;
                int gcol = col0 + wn * 64 + ni * 16 + (lane & 15);
                float vv = acc[mi][ni][r] * scale;
                int bb = grow >> 11, n = grow & (N_ - 1);
                int hh = gcol >> 7,  d = gcol & (HD_ - 1);
                size_t idx = (z < 2)
                    ? ((size_t)(bb * H_ + hh) * N_ + n) * HD_ + d
                    : ((size_t)(bb * H_ + hh) * HD_ + d) * N_ + n;
                Cout[idx] = f2bf(vv);
            }
        }
    }
}

// ---------------------------------------------------------------- output projection GEMM
__global__ __launch_bounds__(256) void gemm_out(const u16* __restrict__ A,
                                                const u16* __restrict__ Bt,
                                                float* __restrict__ Cout,
                                                const float* __restrict__ bias) {
    __shared__ __align__(16) u16 lga[128 * 64];
    __shared__ __align__(16) u16 lgb[128 * 64];
    const int tid  = threadIdx.x;
    const int lane = tid & 63, wave = tid >> 6;
    const int wm = wave >> 1, wn = wave & 1;
    int lin = blockIdx.x + gridDim.x * blockIdx.y;
    int w   = (lin & 7) * 64 + (lin >> 3);
    const int row0 = (w >> 3) * 128, col0 = (w & 7) * 128;

    f32x4 acc[4][4] = {};

    auto stageLds = [&](const u16* G, u16* L, int rowbase, int k0) {
        #pragma unroll
        for (int i = 0; i < 4; i++) {
            int rb = wave * 32 + i * 8;
            int r  = rb + (lane >> 3);
            int cc = (lane & 7) ^ (lane >> 3);
            gl_lds16(G + (size_t)(rowbase + r) * DIM_ + k0 + cc * 8, L + rb * 64);
        }
    };

    for (int k0 = 0; k0 < DIM_; k0 += 64) {
        stageLds(A,  lga, row0, k0);
        stageLds(Bt, lgb, col0, k0);
        __syncthreads();
        #pragma unroll
        for (int kk = 0; kk < 2; kk++) {
            s16x8 af[4], bfr[4];
            #pragma unroll
            for (int mi = 0; mi < 4; mi++) {
                int r = wm * 64 + mi * 16 + (lane & 15);
                int sc = (kk * 4 + (lane >> 4)) ^ (lane & 7);
                af[mi] = *(const s16x8*)(&lga[r * 64 + sc * 8]);
            }
            #pragma unroll
            for (int ni = 0; ni < 4; ni++) {
                int r = wn * 64 + ni * 16 + (lane & 15);
                int sc = (kk * 4 + (lane >> 4)) ^ (lane & 7);
                bfr[ni] = *(const s16x8*)(&lgb[r * 64 + sc * 8]);
            }
            #pragma unroll
            for (int mi = 0; mi < 4; mi++)
                #pragma unroll
                for (int ni = 0; ni < 4; ni++)
                    acc[mi][ni] = __builtin_amdgcn_mfma_f32_16x16x32_bf16(
                        af[mi], bfr[ni], acc[mi][ni], 0, 0, 0);
        }
        __syncthreads();
    }

    #pragma unroll
    for (int mi = 0; mi < 4; mi++) {
        #pragma unroll
        for (int ni = 0; ni < 4; ni++) {
            #pragma unroll
            for (int r = 0; r < 4; r++) {
                int grow = row0 + wm * 64 + mi * 16 + ((lane >> 4) << 2) + r;
                int gcol = col0 + wn * 64 + ni * 16 + (lane & 15);
                Cout[(size_t)grow * DIM_ + gcol] = acc[mi][ni][r] + bias[gcol];
            }
        }
    }
}

// ---------------------------------------------------------------- gated flash attention (swapped)
// R12-proven core; QK^T accumulation split into 2 independent chains per ni
// (4 chains total) to halve exposed dependent-MFMA latency at 2 waves/SIMD.
__global__ __launch_bounds__(256, 2) void attn_swapped(const u16* __restrict__ Qh,
                                                       const u16* __restrict__ Kh,
                                                       const u16* __restrict__ Vt,
                                                       const float* __restrict__ tP,
                                                       u16* __restrict__ xout) {
    __shared__ __align__(16) u16 kt[2][64 * 128];   // K [kv=64][d=128], slot = c ^ mK(r)
    __shared__ __align__(16) u16 vt[2][128 * 64];   // Vt [d=128][kv=64], slot = c ^ mV(r)

    const int tid = threadIdx.x, lane = tid & 63, wave = tid >> 6;
    const int lq = lane & 31, hl = lane >> 5;

    int lin = blockIdx.x + 16 * (blockIdx.y + 8 * blockIdx.z);
    int nl  = (lin & 7) * 64 + (lin >> 3);
    const int qt = nl & 15, hh = (nl >> 4) & 7, b = nl >> 7;
    const int q0 = qt * 128 + wave * 32;
    const int q  = q0 + lq;

    const u16* Qbh = Qh + (size_t)(b * H_ + hh) * N_ * HD_;
    const u16* Kbh = Kh + (size_t)(b * H_ + hh) * N_ * HD_;
    const u16* Vbh = Vt + (size_t)(b * H_ + hh) * HD_ * N_;
    // lane-coalesced gate base: tP4[(((b*32+it)*2+hl)*8 + jj)*2048 + q]
    const f32x4* tp4 = (const f32x4*)tP;
    const size_t tbase0 = ((size_t)(b * 32) * 2 + hl) * 8 * 2048 + q;

    s16x8 qf[8];
    #pragma unroll
    for (int s = 0; s < 8; s++)
        qf[s] = *(const s16x8*)(Qbh + (size_t)q * HD_ + s * 16 + hl * 8);

    auto stageKV = [&](int kv0, int bi) {
        #pragma unroll
        for (int i = 0; i < 4; i++) {
            int rk = wave * 16 + i * 4 + (lane >> 4);
            int ck = (lane & 15) ^ (rk & 15) ^ ((rk & 16) >> 2);
            gl_lds16(Kbh + (size_t)(kv0 + rk) * HD_ + ck * 8,
                     &kt[bi][(wave * 16 + i * 4) * 128]);
            int rv = wave * 32 + i * 8 + (lane >> 3);
            int cv = (lane & 7) ^ (rv & 7) ^ ((rv >> 3) & 3);
            gl_lds16(Vbh + (size_t)rv * N_ + kv0 + cv * 8,
                     &vt[bi][(wave * 32 + i * 8) * 64]);
        }
    };

    const int mKl = (lq & 15) ^ ((lq & 16) >> 2);
    const int mVl = (lq & 7) ^ ((lq >> 3) & 3);

    float m = -3.0e38f, l = 0.f;
    f32x16 aoT[4] = {};

    stageKV(0, 0);
    __syncthreads();

    for (int it = 0; it < N_ / 64; it++) {
        const int kv0 = it * 64, cur = it & 1;
        if (it + 1 < N_ / 64) stageKV(kv0 + 64, cur ^ 1);

        // gate values: 8 lane-coalesced f32x4 loads (32 lanes x 16B dense each)
        const size_t tbase = tbase0 + (size_t)it * (2 * 8 * 2048);
        f32x4 ttv[8];
        #pragma unroll
        for (int jj = 0; jj < 8; jj++)
            ttv[jj] = tp4[tbase + (size_t)jj * 2048];

        // S^T = K · Q^T — 4 independent accumulation chains (2 per ni), summed after
        f32x16 sTa[2] = {}, sTb[2] = {};
        __builtin_amdgcn_s_setprio(1);
        #pragma unroll
        for (int s = 0; s < 4; s++)
            #pragma unroll
            for (int ni = 0; ni < 2; ni++) {
                int r = ni * 32 + lq;
                int slotA = (2 * s + hl) ^ mKl;
                int slotB = (2 * (s + 4) + hl) ^ mKl;
                s16x8 kfa = *(const s16x8*)(&kt[cur][r * 128 + slotA * 8]);
                s16x8 kfb = *(const s16x8*)(&kt[cur][r * 128 + slotB * 8]);
                sTa[ni] = __builtin_amdgcn_mfma_f32_32x32x16_bf16(kfa, qf[s],     sTa[ni], 0, 0, 0);
                sTb[ni] = __builtin_amdgcn_mfma_f32_32x32x16_bf16(kfb, qf[s + 4], sTb[ni], 0, 0, 0);
            }
        __builtin_amdgcn_s_setprio(0);
        f32x16 sT[2];
        sT[0] = sTa[0] + sTb[0];
        sT[1] = sTa[1] + sTb[1];

        float mx = -3.0e38f;
        #pragma unroll
        for (int ni = 0; ni < 2; ni++)
            #pragma unroll
            for (int idx = 0; idx < 16; idx++) {
                float g = sT[ni][idx] * ttv[(ni << 2) | (idx >> 2)][idx & 3];
                sT[ni][idx] = g;
                mx = fmaxf(mx, g);
            }
        mx = fmaxf(mx, __shfl_xor(mx, 32));

        if (__any(mx > m + 8.0f)) {
            float mn = fmaxf(m, mx);
            float sfv = __builtin_amdgcn_exp2f(m - mn);
            m = mn;
            l *= sfv;
            #pragma unroll
            for (int dt = 0; dt < 4; dt++)
                #pragma unroll
                for (int e = 0; e < 16; e++) aoT[dt][e] *= sfv;
        }

        float rs = 0.f;
        #pragma unroll
        for (int ni = 0; ni < 2; ni++)
            #pragma unroll
            for (int e = 0; e < 16; e++) {
                float g = sT[ni][e];
                float p = __builtin_amdgcn_exp2f(g - m);
                rs += p;
                sT[ni][e] = (g != 0.0f) ? p : 0.0f;
            }
        rs += __shfl_xor(rs, 32);
        l += rs;

        s16x8 pfrag[4];
        #pragma unroll
        for (int sp = 0; sp < 4; sp++) {
            const int ni = sp >> 1;
            const int ru = (2 * sp) & 3, rv2 = (2 * sp + 1) & 3;
            unsigned u0 = pk_bf16(sT[ni][ru * 4 + 0], sT[ni][ru * 4 + 1]);
            unsigned u1 = pk_bf16(sT[ni][ru * 4 + 2], sT[ni][ru * 4 + 3]);
            unsigned v0 = pk_bf16(sT[ni][rv2 * 4 + 0], sT[ni][rv2 * 4 + 1]);
            unsigned v1 = pk_bf16(sT[ni][rv2 * 4 + 2], sT[ni][rv2 * 4 + 3]);
            pl32_swap(u0, v0);
            pl32_swap(u1, v1);
            u32x4 w = {u0, u1, v0, v1};
            pfrag[sp] = __builtin_bit_cast(s16x8, w);
        }

        __builtin_amdgcn_s_setprio(1);
        #pragma unroll
        for (int dt = 0; dt < 4; dt++)
            #pragma unroll
            for (int sp = 0; sp < 4; sp++) {
                int r = dt * 32 + lq;
                int slot = (2 * sp + hl) ^ mVl;
                s16x8 vf = *(const s16x8*)(&vt[cur][r * 64 + slot * 8]);
                aoT[dt] = __builtin_amdgcn_mfma_f32_32x32x16_bf16(vf, pfrag[sp], aoT[dt], 0, 0, 0);
            }
        __builtin_amdgcn_s_setprio(0);
        __syncthreads();
    }

    float inv = 1.0f / l;
    u16* orow = xout + ((size_t)(b * N_ + q)) * DIM_ + hh * HD_;
    #pragma unroll
    for (int dt = 0; dt < 4; dt++)
        #pragma unroll
        for (int r2 = 0; r2 < 4; r2++) {
            u16x4 ov;
            #pragma unroll
            for (int e = 0; e < 4; e++)
                ov[e] = f2bf(aoT[dt][r2 * 4 + e] * inv);
            *(u16x4*)(orow + dt * 32 + r2 * 8 + hl * 4) = ov;
        }
}

// ---------------------------------------------------------------- launch
extern "C" void kernel_launch(void* const* d_in, const int* in_sizes, int n_in,
                              void* d_out, int out_size, void* d_ws, size_t ws_size,
                              hipStream_t stream) {
    const float* q     = (const float*)d_in[0];
    const float* k     = (const float*)d_in[1];
    const float* v     = (const float*)d_in[2];
    const float* trans = (const float*)d_in[3];
    const float* Wq    = (const float*)d_in[4];
    const float* Wk    = (const float*)d_in[5];
    const float* Wv    = (const float*)d_in[6];
    const float* Wp    = (const float*)d_in[7];
    const float* bp    = (const float*)d_in[8];
    float* out         = (float*)d_out;

    // workspace map (136 MiB):
    //  [0,16M): xb attention output bf16
    //  [16M..24M): Wq,Wk,Wv,Wp bf16 (contiguous) ; [24..72M): Qh/Kh/Vt (stride 16 MiB)
    //  [72M..120M): qb/kb/vb bf16 (stride 16 MiB; dead after projections)
    //  [72M..136M): tP permuted gates (written AFTER projections consumed qb/kb/vb)
    char* ws = (char*)d_ws;
    u16* xb  = (u16*)(ws);
    u16* wqb = (u16*)(ws + (16u << 20));
    u16* wpb = (u16*)(ws + (22u << 20));
    u16* QhB = (u16*)(ws + (24u << 20));
    u16* KhB = (u16*)(ws + (40u << 20));
    u16* VtB = (u16*)(ws + (56u << 20));
    u16* qb  = (u16*)(ws + (72u << 20));
    float* tP = (float*)(ws + (72u << 20));

    dim3 blk(256);
    prep<<<dim3(14336), blk, 0, stream>>>(q, k, v, Wq, Wk, Wv, Wp, qb, wqb);
    gemm_qkv<<<dim3(8, 64, 3), blk, 0, stream>>>(qb, wqb, QhB);
    gate_permute<<<dim3(4096), blk, 0, stream>>>(trans, tP);
    attn_swapped<<<dim3(16, 8, 4), blk, 0, stream>>>(QhB, KhB, VtB, tP, xb);
    gemm_out<<<dim3(DIM_ / 128, MTOK / 128), blk, 0, stream>>>(xb, wpb, out, bp);
}

// Round 16
// 248.589 us; speedup vs baseline: 1.0063x; 1.0063x over previous
//
#include <hip/hip_runtime.h>
#include <hip/hip_bf16.h>
#include <stdint.h>

// Problem constants (fixed by the reference)
#define B_    4
#define N_    2048
#define DIM_  1024
#define H_    8
#define HD_   128
#define MTOK  (B_ * N_)          // 8192 tokens
#define SCALE_  0.08838834764831845f   // HD^-0.5
#define LOG2E_  1.4426950408889634f
#define QSCALE_ (SCALE_ * LOG2E_)      // folded into Q projection epilogue

typedef unsigned short u16;
typedef __attribute__((ext_vector_type(4)))  float f32x4;
typedef __attribute__((ext_vector_type(16))) float f32x16;
typedef __attribute__((ext_vector_type(8)))  short s16x8;   // 8 bf16 — MFMA A/B frag
typedef __attribute__((ext_vector_type(8)))  u16  u16x8;
typedef __attribute__((ext_vector_type(4)))  u16  u16x4;
typedef __attribute__((ext_vector_type(4)))  unsigned u32x4;

__device__ __forceinline__ u16 f2bf(float f) {
    uint32_t i = __builtin_bit_cast(uint32_t, f);
    return (u16)((i + 0x7FFFu + ((i >> 16) & 1u)) >> 16);   // RNE
}
__device__ __forceinline__ unsigned pk_bf16(float a, float b) {
    unsigned r;
    asm("v_cvt_pk_bf16_f32 %0, %1, %2" : "=v"(r) : "v"(a), "v"(b));
    return r;
}
__device__ __forceinline__ void pl32_swap(unsigned &a, unsigned &b) {
    asm volatile("v_permlane32_swap_b32 %0, %1" : "+v"(a), "+v"(b));
}
__device__ __forceinline__ void gl_lds16(const u16* g, u16* l) {
    __builtin_amdgcn_global_load_lds((const __attribute__((address_space(1))) void*)g,
                                     (__attribute__((address_space(3))) void*)l,
                                     16, 0, 0);
}

// ---------------------------------------------------------------- fused prep kernel
// One launch: [0,12288) cvt3 q/k/v f32->bf16 ; [12288,14336) cvt_w4 weights.
__global__ __launch_bounds__(256) void prep(const float* __restrict__ q,
                                            const float* __restrict__ k,
                                            const float* __restrict__ v,
                                            const float* __restrict__ Wq,
                                            const float* __restrict__ Wk,
                                            const float* __restrict__ Wv,
                                            const float* __restrict__ Wp,
                                            u16* __restrict__ qb,
                                            u16* __restrict__ wqb) {
    const int bid = blockIdx.x, tid = threadIdx.x;
    if (bid < 12288) {
        const int sl = bid >> 12, x = bid & 4095;
        const float* s = sl == 0 ? q : sl == 1 ? k : v;
        u16* d = qb + (size_t)sl * (8u << 20);
        int i = (x * 256 + tid) * 8;
        float4 a = *(const float4*)(s + i);
        float4 b = *(const float4*)(s + i + 4);
        u32x4 w = {pk_bf16(a.x, a.y), pk_bf16(a.z, a.w), pk_bf16(b.x, b.y), pk_bf16(b.z, b.w)};
        *(u16x8*)(d + i) = __builtin_bit_cast(u16x8, w);
    } else {
        const int sub = bid - 12288, sl = sub >> 9, x = sub & 511;
        const float* s = sl == 0 ? Wq : sl == 1 ? Wk : sl == 2 ? Wv : Wp;
        u16* d = wqb + (size_t)sl * (DIM_ * DIM_);
        int i = (x * 256 + tid) * 8;
        float4 a = *(const float4*)(s + i);
        float4 b = *(const float4*)(s + i + 4);
        u32x4 w = {pk_bf16(a.x, a.y), pk_bf16(a.z, a.w), pk_bf16(b.x, b.y), pk_bf16(b.z, b.w)};
        *(u16x8*)(d + i) = __builtin_bit_cast(u16x8, w);
    }
}

// ---------------------------------------------------------------- gate permute (lane-coalesced)
// tP4 (f32x4 units): idx = (((b*32+it)*2+hl)*8 + jj)*2048 + q
//   value[e] = trans[b][q][64*it + 32*(jj>>2) + 8*(jj&3) + 4*hl + e]
__global__ __launch_bounds__(256) void gate_permute(const float* __restrict__ trans,
                                                    float* __restrict__ tP) {
    __shared__ float T[64][68];
    const int sub = blockIdx.x;
    const int it = sub & 31, qc = (sub >> 5) & 31, b = sub >> 10;
    const float* ib = trans + (size_t)b * N_ * N_;
    const int q0 = qc * 64;
    const int lr = threadIdx.x >> 4, lc = threadIdx.x & 15;
    #pragma unroll
    for (int i = 0; i < 4; i++) {
        int row = i * 16 + lr;
        f32x4 vv = *(const f32x4*)(ib + (size_t)(q0 + row) * N_ + it * 64 + lc * 4);
        *(f32x4*)(&T[row][lc * 4]) = vv;
    }
    __syncthreads();
    const int qi = threadIdx.x & 63, grp = threadIdx.x >> 6;
    const int hl = grp & 1, half = grp >> 1;
    f32x4* tp4 = (f32x4*)tP;
    const size_t base = (((size_t)(b * 32 + it) * 2 + hl) * 8 + half * 4) * 2048 + q0 + qi;
    #pragma unroll
    for (int jj2 = 0; jj2 < 4; jj2++) {
        f32x4 vv = *(const f32x4*)(&T[qi][32 * half + 8 * jj2 + 4 * hl]);
        tp4[base + (size_t)jj2 * 2048] = vv;
    }
}

// ---------------------------------------------------------------- fused QKV projection GEMM
// z selects (A, Bt, Cout, scale, epilogue): z<2 -> head-split [B,H,N,HD] (Q,K);
// z==2 -> transposed [B,H,HD,N] (V).  A/C stride 8M u16; Bt stride 1M u16.
__global__ __launch_bounds__(256) void gemm_qkv(const u16* __restrict__ Abase,
                                                const u16* __restrict__ Wbase,
                                                u16* __restrict__ Cbase) {
    __shared__ __align__(16) u16 lga[128 * 64];
    __shared__ __align__(16) u16 lgb[128 * 64];
    const int tid  = threadIdx.x;
    const int lane = tid & 63, wave = tid >> 6;
    const int wm = wave >> 1, wn = wave & 1;
    const int z = blockIdx.z;
    const u16* A  = Abase + (size_t)z * (8u << 20);
    const u16* Bt = Wbase + (size_t)z * (DIM_ * DIM_);
    u16* Cout     = Cbase + (size_t)z * (8u << 20);
    const float scale = (z == 0) ? QSCALE_ : 1.0f;
    int lin = blockIdx.x + gridDim.x * blockIdx.y;
    int w   = (lin & 7) * 64 + (lin >> 3);
    const int row0 = (w >> 3) * 128, col0 = (w & 7) * 128;

    f32x4 acc[4][4] = {};

    auto stageLds = [&](const u16* G, u16* L, int rowbase, int k0) {
        #pragma unroll
        for (int i = 0; i < 4; i++) {
            int rb = wave * 32 + i * 8;
            int r  = rb + (lane >> 3);
            int cc = (lane & 7) ^ (lane >> 3);
            gl_lds16(G + (size_t)(rowbase + r) * DIM_ + k0 + cc * 8, L + rb * 64);
        }
    };

    for (int k0 = 0; k0 < DIM_; k0 += 64) {
        stageLds(A,  lga, row0, k0);
        stageLds(Bt, lgb, col0, k0);
        __syncthreads();
        #pragma unroll
        for (int kk = 0; kk < 2; kk++) {
            s16x8 af[4], bfr[4];
            #pragma unroll
            for (int mi = 0; mi < 4; mi++) {
                int r = wm * 64 + mi * 16 + (lane & 15);
                int sc = (kk * 4 + (lane >> 4)) ^ (lane & 7);
                af[mi] = *(const s16x8*)(&lga[r * 64 + sc * 8]);
            }
            #pragma unroll
            for (int ni = 0; ni < 4; ni++) {
                int r = wn * 64 + ni * 16 + (lane & 15);
                int sc = (kk * 4 + (lane >> 4)) ^ (lane & 7);
                bfr[ni] = *(const s16x8*)(&lgb[r * 64 + sc * 8]);
            }
            #pragma unroll
            for (int mi = 0; mi < 4; mi++)
                #pragma unroll
                for (int ni = 0; ni < 4; ni++)
                    acc[mi][ni] = __builtin_amdgcn_mfma_f32_16x16x32_bf16(
                        af[mi], bfr[ni], acc[mi][ni], 0, 0, 0);
        }
        __syncthreads();
    }

    #pragma unroll
    for (int mi = 0; mi < 4; mi++) {
        #pragma unroll
        for (int ni = 0; ni < 4; ni++) {
            #pragma unroll
            for (int r = 0; r < 4; r++) {
                int grow = row0 + wm * 64 + mi * 16 + ((lane >> 4) << 2) + r;
                int gcol = col0 + wn * 64 + ni * 16 + (lane & 15);
                float vv = acc[mi][ni][r] * scale;
                int bb = grow >> 11, n = grow & (N_ - 1);
                int hh = gcol >> 7,  d = gcol & (HD_ - 1);
                size_t idx = (z < 2)
                    ? ((size_t)(bb * H_ + hh) * N_ + n) * HD_ + d
                    : ((size_t)(bb * H_ + hh) * HD_ + d) * N_ + n;
                Cout[idx] = f2bf(vv);
            }
        }
    }
}

// ---------------------------------------------------------------- output projection GEMM
__global__ __launch_bounds__(256) void gemm_out(const u16* __restrict__ A,
                                                const u16* __restrict__ Bt,
                                                float* __restrict__ Cout,
                                                const float* __restrict__ bias) {
    __shared__ __align__(16) u16 lga[128 * 64];
    __shared__ __align__(16) u16 lgb[128 * 64];
    const int tid  = threadIdx.x;
    const int lane = tid & 63, wave = tid >> 6;
    const int wm = wave >> 1, wn = wave & 1;
    int lin = blockIdx.x + gridDim.x * blockIdx.y;
    int w   = (lin & 7) * 64 + (lin >> 3);
    const int row0 = (w >> 3) * 128, col0 = (w & 7) * 128;

    f32x4 acc[4][4] = {};

    auto stageLds = [&](const u16* G, u16* L, int rowbase, int k0) {
        #pragma unroll
        for (int i = 0; i < 4; i++) {
            int rb = wave * 32 + i * 8;
            int r  = rb + (lane >> 3);
            int cc = (lane & 7) ^ (lane >> 3);
            gl_lds16(G + (size_t)(rowbase + r) * DIM_ + k0 + cc * 8, L + rb * 64);
        }
    };

    for (int k0 = 0; k0 < DIM_; k0 += 64) {
        stageLds(A,  lga, row0, k0);
        stageLds(Bt, lgb, col0, k0);
        __syncthreads();
        #pragma unroll
        for (int kk = 0; kk < 2; kk++) {
            s16x8 af[4], bfr[4];
            #pragma unroll
            for (int mi = 0; mi < 4; mi++) {
                int r = wm * 64 + mi * 16 + (lane & 15);
                int sc = (kk * 4 + (lane >> 4)) ^ (lane & 7);
                af[mi] = *(const s16x8*)(&lga[r * 64 + sc * 8]);
            }
            #pragma unroll
            for (int ni = 0; ni < 4; ni++) {
                int r = wn * 64 + ni * 16 + (lane & 15);
                int sc = (kk * 4 + (lane >> 4)) ^ (lane & 7);
                bfr[ni] = *(const s16x8*)(&lgb[r * 64 + sc * 8]);
            }
            #pragma unroll
            for (int mi = 0; mi < 4; mi++)
                #pragma unroll
                for (int ni = 0; ni < 4; ni++)
                    acc[mi][ni] = __builtin_amdgcn_mfma_f32_16x16x32_bf16(
                        af[mi], bfr[ni], acc[mi][ni], 0, 0, 0);
        }
        __syncthreads();
    }

    #pragma unroll
    for (int mi = 0; mi < 4; mi++) {
        #pragma unroll
        for (int ni = 0; ni < 4; ni++) {
            #pragma unroll
            for (int r = 0; r < 4; r++) {
                int grow = row0 + wm * 64 + mi * 16 + ((lane >> 4) << 2) + r;
                int gcol = col0 + wn * 64 + ni * 16 + (lane & 15);
                Cout[(size_t)grow * DIM_ + gcol] = acc[mi][ni][r] + bias[gcol];
            }
        }
    }
}

// ---------------------------------------------------------------- gated flash attention (swapped)
// R12-proven core (104.7 us): scalar softmax, lane-coalesced tP gate reads.
__global__ __launch_bounds__(256, 2) void attn_swapped(const u16* __restrict__ Qh,
                                                       const u16* __restrict__ Kh,
                                                       const u16* __restrict__ Vt,
                                                       const float* __restrict__ tP,
                                                       u16* __restrict__ xout) {
    __shared__ __align__(16) u16 kt[2][64 * 128];   // K [kv=64][d=128], slot = c ^ mK(r)
    __shared__ __align__(16) u16 vt[2][128 * 64];   // Vt [d=128][kv=64], slot = c ^ mV(r)

    const int tid = threadIdx.x, lane = tid & 63, wave = tid >> 6;
    const int lq = lane & 31, hl = lane >> 5;

    int lin = blockIdx.x + 16 * (blockIdx.y + 8 * blockIdx.z);
    int nl  = (lin & 7) * 64 + (lin >> 3);
    const int qt = nl & 15, hh = (nl >> 4) & 7, b = nl >> 7;
    const int q0 = qt * 128 + wave * 32;
    const int q  = q0 + lq;

    const u16* Qbh = Qh + (size_t)(b * H_ + hh) * N_ * HD_;
    const u16* Kbh = Kh + (size_t)(b * H_ + hh) * N_ * HD_;
    const u16* Vbh = Vt + (size_t)(b * H_ + hh) * HD_ * N_;
    // lane-coalesced gate base: tP4[(((b*32+it)*2+hl)*8 + jj)*2048 + q]
    const f32x4* tp4 = (const f32x4*)tP;
    const size_t tbase0 = ((size_t)(b * 32) * 2 + hl) * 8 * 2048 + q;

    s16x8 qf[8];
    #pragma unroll
    for (int s = 0; s < 8; s++)
        qf[s] = *(const s16x8*)(Qbh + (size_t)q * HD_ + s * 16 + hl * 8);

    auto stageKV = [&](int kv0, int bi) {
        #pragma unroll
        for (int i = 0; i < 4; i++) {
            int rk = wave * 16 + i * 4 + (lane >> 4);
            int ck = (lane & 15) ^ (rk & 15) ^ ((rk & 16) >> 2);
            gl_lds16(Kbh + (size_t)(kv0 + rk) * HD_ + ck * 8,
                     &kt[bi][(wave * 16 + i * 4) * 128]);
            int rv = wave * 32 + i * 8 + (lane >> 3);
            int cv = (lane & 7) ^ (rv & 7) ^ ((rv >> 3) & 3);
            gl_lds16(Vbh + (size_t)rv * N_ + kv0 + cv * 8,
                     &vt[bi][(wave * 32 + i * 8) * 64]);
        }
    };

    const int mKl = (lq & 15) ^ ((lq & 16) >> 2);
    const int mVl = (lq & 7) ^ ((lq >> 3) & 3);

    float m = -3.0e38f, l = 0.f;
    f32x16 aoT[4] = {};

    stageKV(0, 0);
    __syncthreads();

    for (int it = 0; it < N_ / 64; it++) {
        const int kv0 = it * 64, cur = it & 1;
        if (it + 1 < N_ / 64) stageKV(kv0 + 64, cur ^ 1);

        // gate values: 8 lane-coalesced f32x4 loads (32 lanes x 16B dense each)
        const size_t tbase = tbase0 + (size_t)it * (2 * 8 * 2048);
        f32x4 ttv[8];
        #pragma unroll
        for (int jj = 0; jj < 8; jj++)
            ttv[jj] = tp4[tbase + (size_t)jj * 2048];

        f32x16 sT[2] = {};
        __builtin_amdgcn_s_setprio(1);
        #pragma unroll
        for (int s = 0; s < 8; s++)
            #pragma unroll
            for (int ni = 0; ni < 2; ni++) {
                int r = ni * 32 + lq;
                int slot = (2 * s + hl) ^ mKl;
                s16x8 kf = *(const s16x8*)(&kt[cur][r * 128 + slot * 8]);
                sT[ni] = __builtin_amdgcn_mfma_f32_32x32x16_bf16(kf, qf[s], sT[ni], 0, 0, 0);
            }
        __builtin_amdgcn_s_setprio(0);

        float mx = -3.0e38f;
        #pragma unroll
        for (int ni = 0; ni < 2; ni++)
            #pragma unroll
            for (int idx = 0; idx < 16; idx++) {
                float g = sT[ni][idx] * ttv[(ni << 2) | (idx >> 2)][idx & 3];
                sT[ni][idx] = g;
                mx = fmaxf(mx, g);
            }
        mx = fmaxf(mx, __shfl_xor(mx, 32));

        if (__any(mx > m + 8.0f)) {
            float mn = fmaxf(m, mx);
            float sfv = __builtin_amdgcn_exp2f(m - mn);
            m = mn;
            l *= sfv;
            #pragma unroll
            for (int dt = 0; dt < 4; dt++)
                #pragma unroll
                for (int e = 0; e < 16; e++) aoT[dt][e] *= sfv;
        }

        float rs = 0.f;
        #pragma unroll
        for (int ni = 0; ni < 2; ni++)
            #pragma unroll
            for (int e = 0; e < 16; e++) {
                float g = sT[ni][e];
                float p = __builtin_amdgcn_exp2f(g - m);
                rs += p;
                sT[ni][e] = (g != 0.0f) ? p : 0.0f;
            }
        rs += __shfl_xor(rs, 32);
        l += rs;

        s16x8 pfrag[4];
        #pragma unroll
        for (int sp = 0; sp < 4; sp++) {
            const int ni = sp >> 1;
            const int ru = (2 * sp) & 3, rv2 = (2 * sp + 1) & 3;
            unsigned u0 = pk_bf16(sT[ni][ru * 4 + 0], sT[ni][ru * 4 + 1]);
            unsigned u1 = pk_bf16(sT[ni][ru * 4 + 2], sT[ni][ru * 4 + 3]);
            unsigned v0 = pk_bf16(sT[ni][rv2 * 4 + 0], sT[ni][rv2 * 4 + 1]);
            unsigned v1 = pk_bf16(sT[ni][rv2 * 4 + 2], sT[ni][rv2 * 4 + 3]);
            pl32_swap(u0, v0);
            pl32_swap(u1, v1);
            u32x4 w = {u0, u1, v0, v1};
            pfrag[sp] = __builtin_bit_cast(s16x8, w);
        }

        __builtin_amdgcn_s_setprio(1);
        #pragma unroll
        for (int dt = 0; dt < 4; dt++)
            #pragma unroll
            for (int sp = 0; sp < 4; sp++) {
                int r = dt * 32 + lq;
                int slot = (2 * sp + hl) ^ mVl;
                s16x8 vf = *(const s16x8*)(&vt[cur][r * 64 + slot * 8]);
                aoT[dt] = __builtin_amdgcn_mfma_f32_32x32x16_bf16(vf, pfrag[sp], aoT[dt], 0, 0, 0);
            }
        __builtin_amdgcn_s_setprio(0);
        __syncthreads();
    }

    float inv = 1.0f / l;
    u16* orow = xout + ((size_t)(b * N_ + q)) * DIM_ + hh * HD_;
    #pragma unroll
    for (int dt = 0; dt < 4; dt++)
        #pragma unroll
        for (int r2 = 0; r2 < 4; r2++) {
            u16x4 ov;
            #pragma unroll
            for (int e = 0; e < 4; e++)
                ov[e] = f2bf(aoT[dt][r2 * 4 + e] * inv);
            *(u16x4*)(orow + dt * 32 + r2 * 8 + hl * 4) = ov;
        }
}

// ---------------------------------------------------------------- launch
extern "C" void kernel_launch(void* const* d_in, const int* in_sizes, int n_in,
                              void* d_out, int out_size, void* d_ws, size_t ws_size,
                              hipStream_t stream) {
    const float* q     = (const float*)d_in[0];
    const float* k     = (const float*)d_in[1];
    const float* v     = (const float*)d_in[2];
    const float* trans = (const float*)d_in[3];
    const float* Wq    = (const float*)d_in[4];
    const float* Wk    = (const float*)d_in[5];
    const float* Wv    = (const float*)d_in[6];
    const float* Wp    = (const float*)d_in[7];
    const float* bp    = (const float*)d_in[8];
    float* out         = (float*)d_out;

    // workspace map (136 MiB):
    //  [0,16M): xb attention output bf16
    //  [16M..24M): Wq,Wk,Wv,Wp bf16 (contiguous) ; [24..72M): Qh/Kh/Vt (stride 16 MiB)
    //  [72M..120M): qb/kb/vb bf16 (stride 16 MiB; dead after projections)
    //  [72M..136M): tP permuted gates (written AFTER projections consumed qb/kb/vb)
    char* ws = (char*)d_ws;
    u16* xb  = (u16*)(ws);
    u16* wqb = (u16*)(ws + (16u << 20));
    u16* wpb = (u16*)(ws + (22u << 20));
    u16* QhB = (u16*)(ws + (24u << 20));
    u16* KhB = (u16*)(ws + (40u << 20));
    u16* VtB = (u16*)(ws + (56u << 20));
    u16* qb  = (u16*)(ws + (72u << 20));
    float* tP = (float*)(ws + (72u << 20));

    dim3 blk(256);
    prep<<<dim3(14336), blk, 0, stream>>>(q, k, v, Wq, Wk, Wv, Wp, qb, wqb);
    gemm_qkv<<<dim3(8, 64, 3), blk, 0, stream>>>(qb, wqb, QhB);
    gate_permute<<<dim3(4096), blk, 0, stream>>>(trans, tP);
    attn_swapped<<<dim3(16, 8, 4), blk, 0, stream>>>(QhB, KhB, VtB, tP, xb);
    gemm_out<<<dim3(DIM_ / 128, MTOK / 128), blk, 0, stream>>>(xb, wpb, out, bp);
}